// Round 1
// 351.089 us; speedup vs baseline: 1.0180x; 1.0180x over previous
//
#include <hip/hip_runtime.h>
#include <cmath>

#define NLEVELS 16
#define HMASK   0x7FFFFu
#define NPTS    524288
#define NBUCKET 32768          // 32^3 Morton buckets

typedef float v4f __attribute__((ext_vector_type(4)));
typedef float v2f __attribute__((ext_vector_type(2)));

struct LevelParams {
    float cell[NLEVELS];       // fp32 value of 1.0f / (float)RES[l], matching numpy
};

// ---------------------------------------------------------------------------
// Morton bucketing (5 bits/axis)
// ---------------------------------------------------------------------------
__device__ __forceinline__ unsigned spread5(unsigned v) {
    return (v & 1u) | ((v & 2u) << 2) | ((v & 4u) << 4) |
           ((v & 8u) << 6) | ((v & 16u) << 8);
}

__device__ __forceinline__ unsigned morton_key(float x, float y, float z) {
    unsigned bx = min(31u, (unsigned)(x * 32.0f));
    unsigned by = min(31u, (unsigned)(y * 32.0f));
    unsigned bz = min(31u, (unsigned)(z * 32.0f));
    return spread5(bx) | (spread5(by) << 1) | (spread5(bz) << 2);
}

// ---------------------------------------------------------------------------
// EXACT replication of the numpy fp32 chain: hashes + trilinear weights.
// ---------------------------------------------------------------------------
__device__ __forceinline__ void ngp_hash(
    float x, float y, float z, float cell, unsigned* __restrict__ h,
    float& dx, float& dy, float& dz)
{
    const float ux = x / cell;
    const float uy = y / cell;
    const float uz = z / cell;
    const float fx = floorf(ux);
    const float fy = floorf(uy);
    const float fz = floorf(uz);
    dx = ux - fx;
    dy = uy - fy;
    dz = uz - fz;

    const unsigned ix = (unsigned)(int)fx;
    const unsigned iy = (unsigned)(int)fy;
    const unsigned iz = (unsigned)(int)fz;

    const unsigned hx0 = ix;
    const unsigned hx1 = ix + 1u;
    const unsigned hy0 = iy * 2654435761u;
    const unsigned hy1 = (iy + 1u) * 2654435761u;
    const unsigned hz0 = iz * 805459861u;
    const unsigned hz1 = (iz + 1u) * 805459861u;

    h[0] = (hx0 ^ hy0 ^ hz0) & HMASK;
    h[1] = (hx0 ^ hy0 ^ hz1) & HMASK;
    h[2] = (hx0 ^ hy1 ^ hz0) & HMASK;
    h[3] = (hx0 ^ hy1 ^ hz1) & HMASK;
    h[4] = (hx1 ^ hy0 ^ hz0) & HMASK;
    h[5] = (hx1 ^ hy0 ^ hz1) & HMASK;
    h[6] = (hx1 ^ hy1 ^ hz0) & HMASK;
    h[7] = (hx1 ^ hy1 ^ hz1) & HMASK;
}

__device__ __forceinline__ void ngp_weights(
    float dx, float dy, float dz, float* __restrict__ w)
{
    const float wx0 = 1.0f - dx;
    const float wy0 = 1.0f - dy;
    const float wz0 = 1.0f - dz;
    const float p00 = wx0 * wy0;
    const float p01 = wx0 * dy;
    const float p10 = dx * wy0;
    const float p11 = dx * dy;
    w[0] = p00 * wz0;
    w[1] = p00 * dz;
    w[2] = p01 * wz0;
    w[3] = p01 * dz;
    w[4] = p10 * wz0;
    w[5] = p10 * dz;
    w[6] = p11 * wz0;
    w[7] = p11 * dz;
}

__device__ __forceinline__ v2f ngp_combine(
    const float* __restrict__ w, const v2f* __restrict__ e)
{
    // Same accumulation order as the verified baseline (absmax 4.8e-7).
    float c0 = w[0] * e[0].x;
    float c1 = w[0] * e[0].y;
    #pragma unroll
    for (int c = 1; c < 8; ++c) {
        c0 += w[c] * e[c].x;
        c1 += w[c] * e[c].y;
    }
    v2f r = { c0, c1 };
    return r;
}

// ---------------------------------------------------------------------------
// Sort kernel A: histogram of Morton buckets.
// ---------------------------------------------------------------------------
__global__ __launch_bounds__(256) void bucket_count(
    const float* __restrict__ xyz, unsigned* __restrict__ counts)
{
    const int n = blockIdx.x * 256 + threadIdx.x;
    const float x = xyz[3 * n + 0];
    const float y = xyz[3 * n + 1];
    const float z = xyz[3 * n + 2];
    atomicAdd(&counts[morton_key(x, y, z)], 1u);
}

// ---------------------------------------------------------------------------
// Sort kernel B: exclusive prefix sum of 32768 counts -> cursor[].
// One block / 1024 threads. All global traffic is COALESCED (the old version
// did stride-128B per-thread walks = fully scattered lines); the segment-major
// work happens in LDS with an XOR swizzle (idx ^ ((idx>>5)&31)) that is
// conflict-free in BOTH access phases:
//   coalesced  i*1024+t : bank = (t%32) ^ const  -> permutation, 2 lanes/bank
//   segmented  t*32+i   : bank = i ^ (t%32)      -> permutation, 2 lanes/bank
// ---------------------------------------------------------------------------
__global__ __launch_bounds__(1024) void bucket_scan(
    const unsigned* __restrict__ counts, unsigned* __restrict__ cursor)
{
    __shared__ unsigned c[NBUCKET];      // 128 KiB (gfx950 LDS = 160 KiB)
    __shared__ unsigned psum[1024];
    const unsigned t = threadIdx.x;

    #pragma unroll
    for (int i = 0; i < 32; ++i) {
        const unsigned idx = (unsigned)i * 1024u + t;
        c[idx ^ ((idx >> 5) & 31u)] = counts[idx];
    }
    __syncthreads();

    unsigned s = 0;
    #pragma unroll
    for (int i = 0; i < 32; ++i) {
        const unsigned idx = t * 32u + (unsigned)i;
        s += c[idx ^ ((idx >> 5) & 31u)];
    }
    psum[t] = s;
    __syncthreads();

    // inclusive block scan
    for (unsigned off = 1; off < 1024; off <<= 1) {
        unsigned v = 0;
        if (t >= off) v = psum[t - off];
        __syncthreads();
        if (t >= off) psum[t] += v;
        __syncthreads();
    }

    unsigned excl = psum[t] - s;   // exclusive prefix of this thread's segment
    #pragma unroll
    for (int i = 0; i < 32; ++i) {
        const unsigned idx = t * 32u + (unsigned)i;
        const unsigned sw  = idx ^ ((idx >> 5) & 31u);
        const unsigned v = c[sw];
        c[sw] = excl;
        excl += v;
    }
    __syncthreads();

    #pragma unroll
    for (int i = 0; i < 32; ++i) {
        const unsigned idx = (unsigned)i * 1024u + t;
        cursor[idx] = c[idx ^ ((idx >> 5) & 31u)];
    }
}

// ---------------------------------------------------------------------------
// Sort kernel C: scatter points into sorted order, PACKED as (x,y,z,bits(n)).
// One 16B store per point instead of 12B xyz + 4B perm at two locations.
// ---------------------------------------------------------------------------
__global__ __launch_bounds__(256) void bucket_scatter(
    const float* __restrict__ xyz, unsigned* __restrict__ cursor,
    v4f* __restrict__ pts)
{
    const int n = blockIdx.x * 256 + threadIdx.x;
    const float x = xyz[3 * n + 0];
    const float y = xyz[3 * n + 1];
    const float z = xyz[3 * n + 2];
    const unsigned key = morton_key(x, y, z);
    const unsigned p = atomicAdd(&cursor[key], 1u);
    v4f v = { x, y, z, __uint_as_float((unsigned)n) };
    pts[p] = v;
}

// ---------------------------------------------------------------------------
// Phase 1: one block = 256 sorted points x ONE level, level-major dispatch
// (chunk -> XCD mapping is stable across levels since 2048 % 8 == 0, so each
// XCD keeps its xyz slice + its own copy of the current 4 MB table in L2).
//
// NEW: for fine levels (level >= 7) the 8 corner gathers miss L1 with ~zero
// reuse; each would allocate a dead 64B line and occupy an L1 fill slot, and
// throughput collapses to ~MSHR/L2-latency. Issue them as sc0 loads (L1
// bypass, L2 normal) in one asm block with its own s_waitcnt. Coarse levels
// keep normal loads (L1 hits are real there).
//
// NEW: ws stores are non-temporal — 64 MB of streaming output must not evict
// the table from L2.
// ---------------------------------------------------------------------------
__global__ __launch_bounds__(256) void ngp_phase1(
    const v4f* __restrict__ pts,
    const float* __restrict__ tables,
    v2f* __restrict__ ws,             // [L][N] v2f, sorted point order
    LevelParams lp)
{
    const unsigned b = blockIdx.x;
    const int level = (int)(b >> 11);
    const int chunk = (int)(b & 2047u);
    const int p = chunk * 256 + threadIdx.x;

    const v4f q = pts[p];

    const float cell = lp.cell[level];
    const v2f* __restrict__ tab = (const v2f*)tables + ((size_t)level << 19);

    unsigned h[8];
    float dx, dy, dz;
    ngp_hash(q.x, q.y, q.z, cell, h, dx, dy, dz);

    v2f e[8];
    if (level >= 7) {
        // L1-bypass gathers: one asm block, waitcnt inside, outputs are
        // data-dependencies so the consumer cannot be hoisted above it.
        v2f e0, e1, e2, e3, e4, e5, e6, e7;
        const v2f* a0 = tab + h[0];
        const v2f* a1 = tab + h[1];
        const v2f* a2 = tab + h[2];
        const v2f* a3 = tab + h[3];
        const v2f* a4 = tab + h[4];
        const v2f* a5 = tab + h[5];
        const v2f* a6 = tab + h[6];
        const v2f* a7 = tab + h[7];
        asm volatile(
            "global_load_dwordx2 %0, %8, off sc0\n\t"
            "global_load_dwordx2 %1, %9, off sc0\n\t"
            "global_load_dwordx2 %2, %10, off sc0\n\t"
            "global_load_dwordx2 %3, %11, off sc0\n\t"
            "global_load_dwordx2 %4, %12, off sc0\n\t"
            "global_load_dwordx2 %5, %13, off sc0\n\t"
            "global_load_dwordx2 %6, %14, off sc0\n\t"
            "global_load_dwordx2 %7, %15, off sc0\n\t"
            "s_waitcnt vmcnt(0)"
            : "=&v"(e0), "=&v"(e1), "=&v"(e2), "=&v"(e3),
              "=&v"(e4), "=&v"(e5), "=&v"(e6), "=&v"(e7)
            : "v"(a0), "v"(a1), "v"(a2), "v"(a3),
              "v"(a4), "v"(a5), "v"(a6), "v"(a7));
        e[0] = e0; e[1] = e1; e[2] = e2; e[3] = e3;
        e[4] = e4; e[5] = e5; e[6] = e6; e[7] = e7;
    } else {
        #pragma unroll
        for (int c = 0; c < 8; ++c) e[c] = tab[h[c]];
    }

    float w[8];
    ngp_weights(dx, dy, dz, w);

    const v2f r = ngp_combine(w, e);

    __builtin_nontemporal_store(r, &ws[(size_t)level * NPTS + p]);
}

// ---------------------------------------------------------------------------
// Phase 2: un-permute + transpose ws[l][p] -> out[perm[p]][32] via LDS.
// perm now comes from the packed pts[].w. Streaming data (ws in, out out)
// uses non-temporal accesses.
// ---------------------------------------------------------------------------
#define P2S 257

__global__ __launch_bounds__(256) void ngp_phase2(
    const v2f* __restrict__ ws,
    const v4f* __restrict__ pts,
    float* __restrict__ out)
{
    __shared__ v2f lds[NLEVELS * P2S];
    __shared__ unsigned nperm[256];
    const unsigned base = blockIdx.x * 256;
    const unsigned t = threadIdx.x;

    nperm[t] = __float_as_uint(pts[base + t].w);
    #pragma unroll
    for (int l = 0; l < NLEVELS; ++l)
        lds[l * P2S + t] =
            __builtin_nontemporal_load(&ws[(size_t)l * NPTS + base + t]);

    __syncthreads();

    #pragma unroll
    for (int it = 0; it < 8; ++it) {
        const unsigned j = it * 256 + t;
        const unsigned pl = j >> 3;          // local sorted point
        const unsigned k = j & 7u;           // level pair
        const v2f a = lds[(2u * k)      * P2S + pl];
        const v2f b = lds[(2u * k + 1u) * P2S + pl];
        v4f v = { a.x, a.y, b.x, b.y };
        __builtin_nontemporal_store(
            v, (v4f*)(out + (size_t)nperm[pl] * 32 + k * 4));
    }
}

// ---------------------------------------------------------------------------
// Fallback single-kernel (used only if ws_size is too small).
// ---------------------------------------------------------------------------
__global__ __launch_bounds__(256) void ngp_encode(
    const float* __restrict__ xyz,
    const float* __restrict__ tables,
    float* __restrict__ out,
    LevelParams lp)
{
    const int n = blockIdx.x * 256 + threadIdx.x;
    const float x = xyz[3 * n + 0];
    const float y = xyz[3 * n + 1];
    const float z = xyz[3 * n + 2];

    float acc[2 * NLEVELS];
    const v2f* __restrict__ tab_base = (const v2f*)tables;

    #pragma unroll
    for (int l = 0; l < NLEVELS; ++l) {
        unsigned h[8];
        float dx, dy, dz;
        ngp_hash(x, y, z, lp.cell[l], h, dx, dy, dz);
        const v2f* __restrict__ tab = tab_base + ((size_t)l << 19);
        v2f e[8];
        #pragma unroll
        for (int c = 0; c < 8; ++c) e[c] = tab[h[c]];
        float w[8];
        ngp_weights(dx, dy, dz, w);
        const v2f r = ngp_combine(w, e);
        acc[2 * l + 0] = r.x;
        acc[2 * l + 1] = r.y;
    }

    v4f* o4 = (v4f*)(out + (size_t)n * 32);
    #pragma unroll
    for (int j = 0; j < 8; ++j) {
        v4f v = { acc[4 * j + 0], acc[4 * j + 1],
                  acc[4 * j + 2], acc[4 * j + 3] };
        o4[j] = v;
    }
}

extern "C" void kernel_launch(void* const* d_in, const int* in_sizes, int n_in,
                              void* d_out, int out_size, void* d_ws, size_t ws_size,
                              hipStream_t stream) {
    const float* xyz    = (const float*)d_in[0];
    const float* tables = (const float*)d_in[1];
    float* out          = (float*)d_out;

    // Compute RES exactly as CPython does (glibc double exp/log/pow), then
    // cell = 1/RES in fp32 exactly as numpy float32 division.
    LevelParams lp;
    const double B = std::exp((std::log(2048.0) - std::log(16.0)) / 15.0);
    for (int i = 0; i < NLEVELS; ++i) {
        const double r = std::floor(16.0 * std::pow(B, (double)i));
        lp.cell[i] = 1.0f / (float)r;
    }

    // Workspace layout (16B-aligned blocks):
    //   [0, 64MB)        v2f ws_feat[L][N]
    //   [64MB, +8MB)     v4f pts[N]           (x, y, z, bits(orig_index))
    //   [+128KB)         u32 counts[NBUCKET]
    //   [+128KB)         u32 cursor[NBUCKET]
    const size_t off_feat   = 0;
    const size_t off_pts    = off_feat + (size_t)NLEVELS * NPTS * sizeof(v2f);
    const size_t off_counts = off_pts + (size_t)NPTS * sizeof(v4f);
    const size_t off_cursor = off_counts + (size_t)NBUCKET * sizeof(unsigned);
    const size_t ws_needed  = off_cursor + (size_t)NBUCKET * sizeof(unsigned);

    if (ws_size >= ws_needed) {
        char* wsb = (char*)d_ws;
        v2f*      ws_feat = (v2f*)(wsb + off_feat);
        v4f*      pts     = (v4f*)(wsb + off_pts);
        unsigned* counts  = (unsigned*)(wsb + off_counts);
        unsigned* cursor  = (unsigned*)(wsb + off_cursor);

        hipMemsetAsync(counts, 0, NBUCKET * sizeof(unsigned), stream);
        hipLaunchKernelGGL(bucket_count, dim3(NPTS / 256), dim3(256), 0, stream,
                           xyz, counts);
        hipLaunchKernelGGL(bucket_scan, dim3(1), dim3(1024), 0, stream,
                           counts, cursor);
        hipLaunchKernelGGL(bucket_scatter, dim3(NPTS / 256), dim3(256), 0, stream,
                           xyz, cursor, pts);
        hipLaunchKernelGGL(ngp_phase1, dim3(NLEVELS * (NPTS / 256)), dim3(256), 0, stream,
                           pts, tables, ws_feat, lp);
        hipLaunchKernelGGL(ngp_phase2, dim3(NPTS / 256), dim3(256), 0, stream,
                           ws_feat, pts, out);
    } else {
        hipLaunchKernelGGL(ngp_encode, dim3(NPTS / 256), dim3(256), 0, stream,
                           xyz, tables, out, lp);
    }
}